// Round 5
// baseline (377.354 us; speedup 1.0000x reference)
//
#include <hip/hip_runtime.h>

#define NN 100000
#define DD 128
#define EE 640000
#define NPAD 100352   // 98*1024, >= NN
#define GEMM_BLOCKS 1563  // ceil(NN/64)

typedef __bf16 bf16x8 __attribute__((ext_vector_type(8)));
typedef float floatx4 __attribute__((ext_vector_type(4)));

union FragU { int4 i; bf16x8 b; unsigned short us[8]; };

__device__ __forceinline__ unsigned short f2bf(float f) {
    unsigned int u = __float_as_uint(f);
    u += 0x7FFF + ((u >> 16) & 1);   // RNE
    return (unsigned short)(u >> 16);
}
__device__ __forceinline__ float bf2f(unsigned short u) {
    return __uint_as_float(((unsigned int)u) << 16);
}
__device__ __forceinline__ void addbf8(float* acc, int4 raw) {
    unsigned int u0 = (unsigned int)raw.x, u1 = (unsigned int)raw.y;
    unsigned int u2 = (unsigned int)raw.z, u3 = (unsigned int)raw.w;
    acc[0] += __uint_as_float(u0 << 16);
    acc[1] += __uint_as_float(u0 & 0xffff0000u);
    acc[2] += __uint_as_float(u1 << 16);
    acc[3] += __uint_as_float(u1 & 0xffff0000u);
    acc[4] += __uint_as_float(u2 << 16);
    acc[5] += __uint_as_float(u2 & 0xffff0000u);
    acc[6] += __uint_as_float(u3 << 16);
    acc[7] += __uint_as_float(u3 & 0xffff0000u);
}

// ---------------------------------------------------------------------------
// pre_k (fat): [0,2500) histogram deg; [2500,5700) x->bf16 xb (in d_out);
// [5700,5732) W1/W2 -> bf16
// ---------------------------------------------------------------------------
#define HBLK 2500
#define XBLK 3200
__global__ __launch_bounds__(256) void pre_k(
    const int* __restrict__ ei, int* __restrict__ deg,
    const float4* __restrict__ x4, ushort4* __restrict__ xb4,
    const float4* __restrict__ W1, const float4* __restrict__ W2,
    ushort4* __restrict__ wb1, ushort4* __restrict__ wb2) {
    int bid = blockIdx.x;
    if (bid < HBLK) {
        int e = bid * 256 + threadIdx.x;     // EE == 2500*256
        atomicAdd(&deg[ei[EE + e]], 1);
    } else if (bid < HBLK + XBLK) {
        for (int i = (bid - HBLK) * 256 + threadIdx.x; i < NN * 32;
             i += XBLK * 256) {
            float4 v = x4[i];
            ushort4 u;
            u.x = f2bf(v.x); u.y = f2bf(v.y); u.z = f2bf(v.z); u.w = f2bf(v.w);
            xb4[i] = u;
        }
    } else {
        int wb = bid - HBLK - XBLK;          // 0..31
        const float4* src = (wb < 16) ? W1 : W2;
        ushort4* dst = (wb < 16) ? wb1 : wb2;
        int i = (wb & 15) * 256 + threadIdx.x;
        float4 v = src[i];
        ushort4 u;
        u.x = f2bf(v.x); u.y = f2bf(v.y); u.z = f2bf(v.z); u.w = f2bf(v.w);
        dst[i] = u;
    }
}

// ---------------------------------------------------------------------------
// single-block exclusive scan over deg[NPAD] -> cursor; also zero stats[512]
// thread t owns elements [t*98, t*98+98); deg[NN..NPAD)==0 from memset
// ---------------------------------------------------------------------------
__global__ __launch_bounds__(1024) void scan_k(
    const int* __restrict__ deg, int* __restrict__ cursor,
    float* __restrict__ stats) {
    __shared__ int part[1024];
    int t = threadIdx.x;
    if (t < 512) stats[t] = 0.f;
    int base = t * 98;
    int s = 0;
    for (int j = 0; j < 98; ++j) s += deg[base + j];
    part[t] = s;
    __syncthreads();
    for (int off = 1; off < 1024; off <<= 1) {
        int u = (t >= off) ? part[t - off] : 0;
        __syncthreads();
        part[t] += u;
        __syncthreads();
    }
    int run = part[t] - s;   // exclusive prefix of this thread's chunk
    for (int j = 0; j < 98; ++j) {
        int idx = base + j;
        cursor[idx] = run;
        run += deg[idx];
    }
}

__global__ __launch_bounds__(256) void esort_k(const int* __restrict__ ei,
                                               int* __restrict__ cursor,
                                               int* __restrict__ ssrc) {
    int e = blockIdx.x * 256 + threadIdx.x;
    if (e >= EE) return;
    int pos = atomicAdd(&cursor[ei[EE + e]], 1);
    ssrc[pos] = ei[e];
}

// ---------------------------------------------------------------------------
// aggregate: h[n] = bf16((1+eps)*xb[n] + sum xb[src]); 16 lanes/node,
// 4-wide software pipeline on the gather (indep row loads in flight)
// ---------------------------------------------------------------------------
__global__ __launch_bounds__(256) void aggregate_k(
    const unsigned short* __restrict__ xb, const int* __restrict__ ssrc,
    const int* __restrict__ cursor, const int* __restrict__ deg,
    const float* __restrict__ epsp, unsigned short* __restrict__ hout) {
    int tid = blockIdx.x * 256 + threadIdx.x;
    int node = tid >> 4, lane = tid & 15;
    if (node >= NN) return;
    int d = deg[node];
    int start = cursor[node] - d;   // cursor==end after esort
    float ef = 1.0f + epsp[0];

    float acc[8] = {0, 0, 0, 0, 0, 0, 0, 0};
    {
        int4 raw = *(const int4*)(xb + node * 128 + lane * 8);
        addbf8(acc, raw);
#pragma unroll
        for (int i = 0; i < 8; ++i) acc[i] *= ef;
    }
    int j = 0;
    for (; j + 4 <= d; j += 4) {
        int s0 = ssrc[start + j + 0];
        int s1 = ssrc[start + j + 1];
        int s2 = ssrc[start + j + 2];
        int s3 = ssrc[start + j + 3];
        int4 r0 = *(const int4*)(xb + s0 * 128 + lane * 8);
        int4 r1 = *(const int4*)(xb + s1 * 128 + lane * 8);
        int4 r2 = *(const int4*)(xb + s2 * 128 + lane * 8);
        int4 r3 = *(const int4*)(xb + s3 * 128 + lane * 8);
        addbf8(acc, r0); addbf8(acc, r1); addbf8(acc, r2); addbf8(acc, r3);
    }
    for (; j < d; ++j) {
        int s = ssrc[start + j];
        int4 r = *(const int4*)(xb + s * 128 + lane * 8);
        addbf8(acc, r);
    }
    FragU o;
#pragma unroll
    for (int i = 0; i < 8; ++i) o.us[i] = f2bf(acc[i]);
    *(int4*)(hout + node * 128 + lane * 8) = o.i;
}

// ---------------------------------------------------------------------------
// GEMM: 64 rows/block, 256 threads; B staged once in padded LDS; all 4 A
// fragments prefetched to registers.  In place: hio bf16 in -> hio bf16 out
// (each wave reads exactly the 16 rows it writes; load->mfma->store data-dep
//  ordering makes in-place safe).
// MODE 0: A = hio as-is.   MODE 1: A = bf16(relu(BN1(hio))) via sc/sh.
// y = A @ W^T + bias; stats_out[c] += colsum, [128+c] += colsumsq (fp32, pre-round)
// ---------------------------------------------------------------------------
template <int MODE>
__global__ __launch_bounds__(256) void gemm_k(
    unsigned short* hio, const unsigned short* __restrict__ Wb,
    const float* __restrict__ bias, const float* __restrict__ stats_in,
    const float* __restrict__ g, const float* __restrict__ be,
    float* __restrict__ stats_out) {
    __shared__ __align__(16) unsigned short Bs[128][132];  // padded: 2-way = free
    __shared__ __align__(16) float sc[128], sh[128];
    __shared__ __align__(16) float s_sum[128], s_sq[128];

    const int tid = threadIdx.x;
    if (tid < 128) {
        s_sum[tid] = 0.f; s_sq[tid] = 0.f;
        if (MODE == 1) {
            const float inv = 1.0f / (float)NN;
            float mean = stats_in[tid] * inv;
            float var = stats_in[128 + tid] * inv - mean * mean;
            float s = g[tid] * rsqrtf(var + 1e-5f);
            sc[tid] = s;
            sh[tid] = be[tid] - mean * s;
        }
    }
    // stage B (row-major bf16) into padded LDS
#pragma unroll
    for (int it = 0; it < 8; ++it) {
        int idx = it * 256 + tid;          // 16B chunk id
        int row = idx >> 4, c8 = (idx & 15) * 8;
        int4 v = *(const int4*)(Wb + row * 128 + c8);
        *(int4*)&Bs[row][c8] = v;
    }

    const int w = tid >> 6, l = tid & 63, m = l & 15, q = l >> 4;
    const int rA = blockIdx.x * 64 + w * 16 + m;
    const int rAc = (rA < NN) ? rA : (NN - 1);   // clamp; garbage rows masked at store

    // prefetch all 4 A fragments (independent 16B loads in flight)
    FragU a[4];
#pragma unroll
    for (int kc = 0; kc < 4; ++kc)
        a[kc].i = *(const int4*)(hio + rAc * 128 + kc * 32 + q * 8);

    __syncthreads();   // Bs + sc/sh ready

    if (MODE == 1) {
#pragma unroll
        for (int kc = 0; kc < 4; ++kc) {
            int k0 = kc * 32 + q * 8;
            float4 sA = *(const float4*)&sc[k0], sB = *(const float4*)&sc[k0 + 4];
            float4 hA = *(const float4*)&sh[k0], hB = *(const float4*)&sh[k0 + 4];
            FragU u = a[kc];
            u.us[0] = f2bf(fmaxf(bf2f(u.us[0]) * sA.x + hA.x, 0.f));
            u.us[1] = f2bf(fmaxf(bf2f(u.us[1]) * sA.y + hA.y, 0.f));
            u.us[2] = f2bf(fmaxf(bf2f(u.us[2]) * sA.z + hA.z, 0.f));
            u.us[3] = f2bf(fmaxf(bf2f(u.us[3]) * sA.w + hA.w, 0.f));
            u.us[4] = f2bf(fmaxf(bf2f(u.us[4]) * sB.x + hB.x, 0.f));
            u.us[5] = f2bf(fmaxf(bf2f(u.us[5]) * sB.y + hB.y, 0.f));
            u.us[6] = f2bf(fmaxf(bf2f(u.us[6]) * sB.z + hB.z, 0.f));
            u.us[7] = f2bf(fmaxf(bf2f(u.us[7]) * sB.w + hB.w, 0.f));
            a[kc] = u;
        }
    }

    floatx4 acc[8];
#pragma unroll
    for (int ct = 0; ct < 8; ++ct) acc[ct] = (floatx4)0.0f;

#pragma unroll
    for (int kc = 0; kc < 4; ++kc) {
        int k0 = kc * 32 + q * 8;
#pragma unroll
        for (int ct = 0; ct < 8; ++ct) {
            bf16x8 b = *(const bf16x8*)&Bs[ct * 16 + m][k0];
            acc[ct] = __builtin_amdgcn_mfma_f32_16x16x32_bf16(a[kc].b, b, acc[ct], 0, 0, 0);
        }
    }

    // epilogue: bias, in-place bf16 store, fp32 column stats
#pragma unroll
    for (int ct = 0; ct < 8; ++ct) {
        int col = ct * 16 + m;
        float bc = bias[col];
        float ps = 0.f, pq = 0.f;
#pragma unroll
        for (int i = 0; i < 4; ++i) {
            int rg = blockIdx.x * 64 + w * 16 + q * 4 + i;
            if (rg < NN) {
                float yv = acc[ct][i] + bc;
                hio[rg * 128 + col] = f2bf(yv);
                ps += yv;
                pq += yv * yv;
            }
        }
        atomicAdd(&s_sum[col], ps);
        atomicAdd(&s_sq[col], pq);
    }
    __syncthreads();
    if (tid < 128) {
        unsafeAtomicAdd(&stats_out[tid], s_sum[tid]);
        unsafeAtomicAdd(&stats_out[128 + tid], s_sq[tid]);
    }
}

// ---------------------------------------------------------------------------
// final BN + ReLU: read y2 bf16, write fp32 d_out
// ---------------------------------------------------------------------------
__global__ __launch_bounds__(256) void bn_final_k(
    const unsigned short* __restrict__ y, float* __restrict__ out,
    const float* __restrict__ stats, const float* __restrict__ g,
    const float* __restrict__ beta) {
    __shared__ __align__(16) float sc[128];
    __shared__ __align__(16) float sh[128];
    int t = threadIdx.x;
    if (t < 128) {
        const float inv = 1.0f / (float)NN;
        float mean = stats[t] * inv;
        float var = stats[128 + t] * inv - mean * mean;
        float s = g[t] * rsqrtf(var + 1e-5f);
        sc[t] = s;
        sh[t] = beta[t] - mean * s;
    }
    __syncthreads();
    int i = blockIdx.x * 256 + t;          // exactly NN*16 chunks
    int c8 = (i & 15) * 8;
    int4 raw = ((const int4*)y)[i];
    float v[8] = {0, 0, 0, 0, 0, 0, 0, 0};
    addbf8(v, raw);
    float4 sA = *(const float4*)&sc[c8], sB = *(const float4*)&sc[c8 + 4];
    float4 hA = *(const float4*)&sh[c8], hB = *(const float4*)&sh[c8 + 4];
    float4 o0, o1;
    o0.x = fmaxf(v[0] * sA.x + hA.x, 0.f);
    o0.y = fmaxf(v[1] * sA.y + hA.y, 0.f);
    o0.z = fmaxf(v[2] * sA.z + hA.z, 0.f);
    o0.w = fmaxf(v[3] * sA.w + hA.w, 0.f);
    o1.x = fmaxf(v[4] * sB.x + hB.x, 0.f);
    o1.y = fmaxf(v[5] * sB.y + hB.y, 0.f);
    o1.z = fmaxf(v[6] * sB.z + hB.z, 0.f);
    o1.w = fmaxf(v[7] * sB.w + hB.w, 0.f);
    ((float4*)out)[i * 2] = o0;
    ((float4*)out)[i * 2 + 1] = o1;
}

// ---------------------------------------------------------------------------
extern "C" void kernel_launch(void* const* d_in, const int* in_sizes, int n_in,
                              void* d_out, int out_size, void* d_ws, size_t ws_size,
                              hipStream_t stream) {
    const float* x   = (const float*)d_in[0];
    const int* ei    = (const int*)d_in[1];   // int64 in ref -> int32 from harness
    const float* eps = (const float*)d_in[2];
    const float* W1  = (const float*)d_in[3];
    const float* b1  = (const float*)d_in[4];
    const float* g1  = (const float*)d_in[5];
    const float* be1 = (const float*)d_in[6];
    const float* W2  = (const float*)d_in[7];
    const float* b2  = (const float*)d_in[8];
    const float* g2  = (const float*)d_in[9];
    const float* be2 = (const float*)d_in[10];
    float* out = (float*)d_out;

    // ws (~29 MB): deg | cursor | ssrc | hbuf | wb1 | wb2 | stats
    // xb (bf16 x) in first half of d_out: dead before bn_final writes out.
    // hbuf carries h1 -> y1(bf16, in place) -> y2(bf16, in place).
    int* deg    = (int*)d_ws;                                 // NPAD
    int* cursor = deg + NPAD;                                 // NPAD
    int* ssrc   = cursor + NPAD;                              // EE
    unsigned short* hbuf = (unsigned short*)(ssrc + EE);      // N*128 bf16
    unsigned short* wb1  = hbuf + (size_t)NN * DD;            // 16384
    unsigned short* wb2  = wb1 + 16384;                       // 16384
    float* stats = (float*)(wb2 + 16384);                     // 512
    unsigned short* xb = (unsigned short*)d_out;              // N*128 bf16

    hipMemsetAsync(deg, 0, NPAD * sizeof(int), stream);

    pre_k<<<HBLK + XBLK + 32, 256, 0, stream>>>(
        ei, deg, (const float4*)x, (ushort4*)xb,
        (const float4*)W1, (const float4*)W2, (ushort4*)wb1, (ushort4*)wb2);
    scan_k<<<1, 1024, 0, stream>>>(deg, cursor, stats);
    esort_k<<<(EE + 255) / 256, 256, 0, stream>>>(ei, cursor, ssrc);
    aggregate_k<<<NN * 16 / 256, 256, 0, stream>>>(xb, ssrc, cursor, deg, eps,
                                                   hbuf);
    gemm_k<0><<<GEMM_BLOCKS, 256, 0, stream>>>(hbuf, wb1, b1, nullptr, nullptr,
                                               nullptr, stats);
    gemm_k<1><<<GEMM_BLOCKS, 256, 0, stream>>>(hbuf, wb2, b2, stats, g1, be1,
                                               stats + 256);
    bn_final_k<<<NN * 16 / 256, 256, 0, stream>>>(hbuf, out, stats + 256, g2,
                                                  be2);
}